// Round 1
// baseline (94796.124 us; speedup 1.0000x reference)
//
#include <hip/hip_runtime.h>

#define BB 16
#define TT 1500
#define DD 512
#define HH 512
#define NG3 1536
#define GM (BB * TT)   /* 24000 */
#define GK 512
#define GN NG3
#define LNEPS 1e-5f
#define RWG 96
#define CPW 16

// ---------------- helpers ----------------
__device__ __forceinline__ float sigmoidf_(float x) { return 1.f / (1.f + __expf(-x)); }
__device__ __forceinline__ float tanhf_(float x) {
  x = fminf(15.f, fmaxf(-15.f, x));
  float e = __expf(2.f * x);
  return (e - 1.f) / (e + 1.f);
}
// sum across the 16-lane group (lane & 15)
__device__ __forceinline__ float red16_(float v) {
  v += __shfl_xor(v, 1, 64);
  v += __shfl_xor(v, 2, 64);
  v += __shfl_xor(v, 4, 64);
  v += __shfl_xor(v, 8, 64);
  return v;
}

// ---------------- big GEMM: C[M,N] = A[M,K] @ W[N,K]^T (fp32) ----------------
__global__ __launch_bounds__(256) void gemm_nt(const float* __restrict__ A,
                                               const float* __restrict__ W,
                                               float* __restrict__ C) {
  __shared__ __align__(16) float As[32][68];
  __shared__ __align__(16) float Ws[32][68];
  const int m0 = blockIdx.x * 64;
  const int n0 = blockIdx.y * 64;
  const int tid = threadIdx.x;
  const int tm = tid & 15, tn = tid >> 4;
  float acc[4][4] = {};
  for (int k0 = 0; k0 < GK; k0 += 32) {
#pragma unroll
    for (int u = 0; u < 2; ++u) {
      int idx = tid + u * 256;
      int r = idx >> 3;
      int kq = (idx & 7) * 4;
      float4 a = *reinterpret_cast<const float4*>(&A[(size_t)(m0 + r) * GK + k0 + kq]);
      As[kq + 0][r] = a.x; As[kq + 1][r] = a.y; As[kq + 2][r] = a.z; As[kq + 3][r] = a.w;
      float4 w = *reinterpret_cast<const float4*>(&W[(size_t)(n0 + r) * GK + k0 + kq]);
      Ws[kq + 0][r] = w.x; Ws[kq + 1][r] = w.y; Ws[kq + 2][r] = w.z; Ws[kq + 3][r] = w.w;
    }
    __syncthreads();
#pragma unroll
    for (int kk = 0; kk < 32; ++kk) {
      float a[4], w[4];
      *reinterpret_cast<float4*>(a) = *reinterpret_cast<const float4*>(&As[kk][tm * 4]);
      *reinterpret_cast<float4*>(w) = *reinterpret_cast<const float4*>(&Ws[kk][tn * 4]);
#pragma unroll
      for (int i = 0; i < 4; ++i)
#pragma unroll
        for (int q = 0; q < 4; ++q)
          acc[i][q] = fmaf(a[i], w[q], acc[i][q]);
    }
    __syncthreads();
  }
#pragma unroll
  for (int i = 0; i < 4; ++i) {
    float4 v = make_float4(acc[i][0], acc[i][1], acc[i][2], acc[i][3]);
    *reinterpret_cast<float4*>(&C[(size_t)(m0 + tm * 4 + i) * GN + n0 + tn * 4]) = v;
  }
}

// ---------------- grid barrier (persistent kernel, 96 WGs co-resident) ----------------
__device__ __forceinline__ void grid_bar(unsigned* cnt, unsigned target) {
  __syncthreads();
  __threadfence();
  if (threadIdx.x == 0) {
    __hip_atomic_fetch_add(cnt, 1u, __ATOMIC_ACQ_REL, __HIP_MEMORY_SCOPE_AGENT);
    while (__hip_atomic_load(cnt, __ATOMIC_ACQUIRE, __HIP_MEMORY_SCOPE_AGENT) < target) {
      __builtin_amdgcn_s_sleep(2);
    }
  }
  __syncthreads();
  __threadfence();
}

// XOR-swizzled chunk offset inside a [512]-float LDS row (float4 chunks)
__device__ __forceinline__ int hswz(int b, int kc) { return ((kc ^ (b & 7)) << 2); }

// ---------------- persistent GRU layer scan ----------------
__global__ __launch_bounds__(256, 1) void gru_layer(
    const float* __restrict__ Wh,    // [1536][512] this layer
    const float* __restrict__ X,     // [BB][TT][1536] precomputed input gates
    const float* __restrict__ lnw,   // [3][512] this layer
    const float* __restrict__ lnb,   // [3][512]
    const float* __restrict__ resid, // null (layer0) or h0 [BB][TT][HH]
    float* __restrict__ hout,        // h0 (layer0) or out (layer1): [BB][TT][HH]
    float* __restrict__ Gb,          // [2][BB][1536] double-buffered pre-acts
    unsigned* __restrict__ cnt) {
  __shared__ __align__(16) float wh_s[CPW][512];  // persistent Wh slice
  __shared__ __align__(16) float h_s[BB][512];    // private copy of h (xor-swizzled rows)

  const int tid = threadIdx.x;
  const int wg = blockIdx.x;
  const int j0 = wg * CPW;

  // load Wh slice once
  for (int idx = tid; idx < CPW * 128; idx += 256) {
    int c = idx >> 7;
    int kq = (idx & 127) * 4;
    *reinterpret_cast<float4*>(&wh_s[c][kq]) =
        *reinterpret_cast<const float4*>(&Wh[(size_t)(j0 + c) * 512 + kq]);
  }
  // h0 = 0
  for (int idx = tid; idx < BB * 512; idx += 256) h_s[idx >> 9][idx & 511] = 0.f;
  __syncthreads();

  const int b1 = tid & 15;   // phase-1: batch row
  const int c1 = tid >> 4;   // phase-1: column within slice
  const int lane = tid & 63;
  const int b2 = (tid >> 6) * 4 + (lane >> 4);  // phase-2: batch row (16 lanes each)
  const int l16 = lane & 15;
  const unsigned nwg = gridDim.x;

  for (int t = 0; t < TT; ++t) {
    // ---- phase 1: h_gates for our 16 columns ----
    float acc = 0.f;
#pragma unroll 8
    for (int kc = 0; kc < 128; ++kc) {
      float hv[4], wv[4];
      *reinterpret_cast<float4*>(hv) = *reinterpret_cast<const float4*>(&h_s[b1][hswz(b1, kc)]);
      *reinterpret_cast<float4*>(wv) = *reinterpret_cast<const float4*>(&wh_s[c1][kc << 2]);
      acc = fmaf(hv[0], wv[0], acc);
      acc = fmaf(hv[1], wv[1], acc);
      acc = fmaf(hv[2], wv[2], acc);
      acc = fmaf(hv[3], wv[3], acc);
    }
    const int j = j0 + c1;
    float* Gw = Gb + (size_t)(t & 1) * (BB * NG3);
    if (j < 1024) acc += X[((size_t)b1 * TT + t) * NG3 + j];  // r,z: add x-gate now; n: keep raw h·Whn
    Gw[b1 * NG3 + j] = acc;

    grid_bar(cnt, (unsigned)(t + 1) * nwg);

    // ---- phase 2: redundant LN + gates + h update (every WG, all 16 b) ----
    const float* Grow = Gb + (size_t)(t & 1) * (BB * NG3) + (size_t)b2 * NG3;
    const float* Xrow = X + ((size_t)b2 * TT + t) * NG3;

    float gr[32], gz[32], np_[32];
    float s = 0.f, s2 = 0.f;
#pragma unroll
    for (int i = 0; i < 8; ++i) {
      int j2 = l16 * 4 + i * 64;
      *reinterpret_cast<float4*>(&gr[i * 4]) = *reinterpret_cast<const float4*>(&Grow[j2]);
#pragma unroll
      for (int q = 0; q < 4; ++q) { float v = gr[i * 4 + q]; s += v; s2 += v * v; }
    }
    s = red16_(s); s2 = red16_(s2);
    const float mr = s * (1.f / 512.f);
    const float rsr = rsqrtf(s2 * (1.f / 512.f) - mr * mr + LNEPS);

    s = 0.f; s2 = 0.f;
#pragma unroll
    for (int i = 0; i < 8; ++i) {
      int j2 = l16 * 4 + i * 64;
      float gn[4], xn[4];
      *reinterpret_cast<float4*>(gn) = *reinterpret_cast<const float4*>(&Grow[1024 + j2]);
      *reinterpret_cast<float4*>(xn) = *reinterpret_cast<const float4*>(&Xrow[1024 + j2]);
#pragma unroll
      for (int q = 0; q < 4; ++q) {
        float rv = sigmoidf_((gr[i * 4 + q] - mr) * rsr * lnw[j2 + q] + lnb[j2 + q]);
        float v = xn[q] + rv * gn[q];
        np_[i * 4 + q] = v; s += v; s2 += v * v;
      }
    }
    s = red16_(s); s2 = red16_(s2);
    const float mn = s * (1.f / 512.f);
    const float rsn = rsqrtf(s2 * (1.f / 512.f) - mn * mn + LNEPS);

    s = 0.f; s2 = 0.f;
#pragma unroll
    for (int i = 0; i < 8; ++i) {
      int j2 = l16 * 4 + i * 64;
      *reinterpret_cast<float4*>(&gz[i * 4]) = *reinterpret_cast<const float4*>(&Grow[512 + j2]);
#pragma unroll
      for (int q = 0; q < 4; ++q) { float v = gz[i * 4 + q]; s += v; s2 += v * v; }
    }
    s = red16_(s); s2 = red16_(s2);
    const float mz = s * (1.f / 512.f);
    const float rsz = rsqrtf(s2 * (1.f / 512.f) - mz * mz + LNEPS);

#pragma unroll
    for (int i = 0; i < 8; ++i) {
      int j2 = l16 * 4 + i * 64;
      int kc2 = l16 + i * 16;
      float hold[4], hv[4], rs4[4];
      *reinterpret_cast<float4*>(hold) = *reinterpret_cast<const float4*>(&h_s[b2][hswz(b2, kc2)]);
      if (resid)
        *reinterpret_cast<float4*>(rs4) =
            *reinterpret_cast<const float4*>(&resid[((size_t)b2 * TT + t) * HH + j2]);
#pragma unroll
      for (int q = 0; q < 4; ++q) {
        float z = sigmoidf_((gz[i * 4 + q] - mz) * rsz * lnw[512 + j2 + q] + lnb[512 + j2 + q]);
        float n = tanhf_((np_[i * 4 + q] - mn) * rsn * lnw[1024 + j2 + q] + lnb[1024 + j2 + q]);
        float hnv = (1.f - z) * n + z * hold[q];
        if (resid) hnv += rs4[q];
        hv[q] = hnv;
      }
      *reinterpret_cast<float4*>(&h_s[b2][hswz(b2, kc2)]) = *reinterpret_cast<const float4*>(hv);
      if (wg == b2) {
        *reinterpret_cast<float4*>(&hout[((size_t)b2 * TT + t) * HH + j2]) =
            *reinterpret_cast<const float4*>(hv);
      }
    }
    __syncthreads();  // h_s updated before next phase-1 reads
  }
}

// ---------------- launch ----------------
extern "C" void kernel_launch(void* const* d_in, const int* in_sizes, int n_in,
                              void* d_out, int out_size, void* d_ws, size_t ws_size,
                              hipStream_t stream) {
  (void)in_sizes; (void)n_in; (void)out_size; (void)ws_size;
  const float* x   = (const float*)d_in[0];
  const float* Wi  = (const float*)d_in[1];  // [2][1536][512]
  const float* Wh  = (const float*)d_in[2];  // [2][1536][512]
  const float* lnw = (const float*)d_in[3];  // [2][3][512]
  const float* lnb = (const float*)d_in[4];
  float* out = (float*)d_out;

  float* X  = (float*)d_ws;                       // [24000][1536]
  float* h0 = X + (size_t)GM * NG3;               // [24000][512]
  float* Gb = h0 + (size_t)GM * HH;               // [2][16][1536]
  unsigned* cnt = (unsigned*)(Gb + 2 * BB * NG3); // 2 counters, 128B apart

  hipMemsetAsync(cnt, 0, 256, stream);

  dim3 ggrid(GM / 64, GN / 64);
  // layer 0 input gates
  gemm_nt<<<ggrid, 256, 0, stream>>>(x, Wi, X);
  // layer 0 scan
  gru_layer<<<RWG, 256, 0, stream>>>(Wh, X, lnw, lnb, nullptr, h0, Gb, cnt);
  // layer 1 input gates (reuse X buffer)
  gemm_nt<<<ggrid, 256, 0, stream>>>(h0, Wi + (size_t)NG3 * DD, X);
  // layer 1 scan (+residual), writes final output
  gru_layer<<<RWG, 256, 0, stream>>>(Wh + (size_t)NG3 * HH, X, lnw + 3 * 512, lnb + 3 * 512,
                                     h0, out, Gb, cnt + 32);
}

// Round 2
// 90352.625 us; speedup vs baseline: 1.0492x; 1.0492x over previous
//
#include <hip/hip_runtime.h>

#define BB 16
#define TT 1500
#define DD 512
#define HH 512
#define NG3 1536
#define GM (BB * TT)   /* 24000 */
#define GK 512
#define GN NG3
#define LNEPS 1e-5f
#define RWG 96
#define CPW 16
#define FLAGSTRIDE 64  /* uints -> 256B per flag line */

// ---------------- helpers ----------------
__device__ __forceinline__ float sigmoidf_(float x) { return 1.f / (1.f + __expf(-x)); }
__device__ __forceinline__ float tanhf_(float x) {
  x = fminf(15.f, fmaxf(-15.f, x));
  float e = __expf(2.f * x);
  return (e - 1.f) / (e + 1.f);
}
// sum across each 16-lane group (lane & 15)
__device__ __forceinline__ float red16_(float v) {
  v += __shfl_xor(v, 1, 64);
  v += __shfl_xor(v, 2, 64);
  v += __shfl_xor(v, 4, 64);
  v += __shfl_xor(v, 8, 64);
  return v;
}
// XOR-swizzled physical float4-chunk index for a [512]-float LDS row
__device__ __forceinline__ int physc(int lc) { return (lc & ~7) | ((lc ^ (lc >> 3)) & 7); }

// ---------------- big GEMM: C[M,N] = A[M,K] @ W[N,K]^T (fp32) ----------------
__global__ __launch_bounds__(256) void gemm_nt(const float* __restrict__ A,
                                               const float* __restrict__ W,
                                               float* __restrict__ C) {
  __shared__ __align__(16) float As[32][68];
  __shared__ __align__(16) float Ws[32][68];
  const int m0 = blockIdx.x * 64;
  const int n0 = blockIdx.y * 64;
  const int tid = threadIdx.x;
  const int tm = tid & 15, tn = tid >> 4;
  float acc[4][4] = {};
  for (int k0 = 0; k0 < GK; k0 += 32) {
#pragma unroll
    for (int u = 0; u < 2; ++u) {
      int idx = tid + u * 256;
      int r = idx >> 3;
      int kq = (idx & 7) * 4;
      float4 a = *reinterpret_cast<const float4*>(&A[(size_t)(m0 + r) * GK + k0 + kq]);
      As[kq + 0][r] = a.x; As[kq + 1][r] = a.y; As[kq + 2][r] = a.z; As[kq + 3][r] = a.w;
      float4 w = *reinterpret_cast<const float4*>(&W[(size_t)(n0 + r) * GK + k0 + kq]);
      Ws[kq + 0][r] = w.x; Ws[kq + 1][r] = w.y; Ws[kq + 2][r] = w.z; Ws[kq + 3][r] = w.w;
    }
    __syncthreads();
#pragma unroll
    for (int kk = 0; kk < 32; ++kk) {
      float a[4], w[4];
      *reinterpret_cast<float4*>(a) = *reinterpret_cast<const float4*>(&As[kk][tm * 4]);
      *reinterpret_cast<float4*>(w) = *reinterpret_cast<const float4*>(&Ws[kk][tn * 4]);
#pragma unroll
      for (int i = 0; i < 4; ++i)
#pragma unroll
        for (int q = 0; q < 4; ++q)
          acc[i][q] = fmaf(a[i], w[q], acc[i][q]);
    }
    __syncthreads();
  }
#pragma unroll
  for (int i = 0; i < 4; ++i) {
    float4 v = make_float4(acc[i][0], acc[i][1], acc[i][2], acc[i][3]);
    *reinterpret_cast<float4*>(&C[(size_t)(m0 + tm * 4 + i) * GN + n0 + tn * 4]) = v;
  }
}

// ---------------- contention-free flag barrier ----------------
// Each WG stores t+1 to its own padded flag line; all WGs poll the 96 lines
// in parallel (thread i polls flag i). Monotonic values -> no reset needed.
__device__ __forceinline__ void grid_bar(unsigned* flags, int wg, unsigned tval) {
  __syncthreads();
  __threadfence();  // make this WG's Gb writes visible agent-wide
  if (threadIdx.x == 0)
    __hip_atomic_store(&flags[(size_t)wg * FLAGSTRIDE], tval, __ATOMIC_RELAXED,
                       __HIP_MEMORY_SCOPE_AGENT);
  if (threadIdx.x < RWG) {
    while (__hip_atomic_load(&flags[(size_t)threadIdx.x * FLAGSTRIDE], __ATOMIC_RELAXED,
                             __HIP_MEMORY_SCOPE_AGENT) < tval)
      __builtin_amdgcn_s_sleep(1);
  }
  __syncthreads();
  __threadfence();  // acquire side: subsequent reads see remote Gb writes
}

// ---------------- persistent GRU layer scan ----------------
__global__ __launch_bounds__(256, 1) void gru_layer(
    const float* __restrict__ Wh,    // [1536][512] this layer
    const float* __restrict__ X,     // [BB][TT][1536] precomputed input gates
    const float* __restrict__ lnw,   // [3][512] this layer
    const float* __restrict__ lnb,   // [3][512]
    const float* __restrict__ resid, // null (layer0) or h0 [BB][TT][HH]
    float* __restrict__ hout,        // h0 (layer0) or out (layer1): [BB][TT][HH]
    float* __restrict__ Gb,          // [2][BB][1536] double-buffered pre-acts
    unsigned* __restrict__ flags) {
  __shared__ __align__(16) float h_s[BB][512];  // private copy of h (chunk-swizzled rows)

  const int tid = threadIdx.x;
  const int wg = blockIdx.x;
  const int j0 = wg * CPW;

  const int lane = tid & 63;
  const int wv = tid >> 6;
  const int ks = lane & 15;       // K-chunk index: k in [ks*32, ks*32+32)
  const int cq = lane >> 4;       // column within wave (0..3)
  const int col = j0 + wv * 4 + cq;

  // persistent weights in registers: Wh[col][ks*32 .. +32)
  float wreg[32];
#pragma unroll
  for (int q = 0; q < 8; ++q)
    *reinterpret_cast<float4*>(&wreg[q * 4]) =
        *reinterpret_cast<const float4*>(&Wh[(size_t)col * 512 + ks * 32 + q * 4]);

  // h0 = 0
  for (int idx = tid; idx < BB * 512; idx += 256) (&h_s[0][0])[idx] = 0.f;
  __syncthreads();

  const int b2 = (tid >> 6) * 4 + (lane >> 4);  // phase-2: batch row (16 lanes each)
  const int l16 = lane & 15;

  for (int t = 0; t < TT; ++t) {
    // ---- phase 1: h_gates, thread = (col, K-chunk), reduce over 16 chunks ----
    float gout = 0.f;
#pragma unroll 4
    for (int b = 0; b < 16; ++b) {
      const float* hrow = &h_s[b][0];
      float p = 0.f;
#pragma unroll
      for (int i = 0; i < 8; ++i) {
        float hv[4];
        *reinterpret_cast<float4*>(hv) =
            *reinterpret_cast<const float4*>(&hrow[(((ks << 3) | ((i ^ ks) & 7)) << 2)]);
        p = fmaf(hv[0], wreg[i * 4 + 0], p);
        p = fmaf(hv[1], wreg[i * 4 + 1], p);
        p = fmaf(hv[2], wreg[i * 4 + 2], p);
        p = fmaf(hv[3], wreg[i * 4 + 3], p);
      }
      p = red16_(p);
      if (ks == b) gout = p;  // each lane keeps the row matching its ks
    }
    float* Gw = Gb + (size_t)(t & 1) * (BB * NG3);
    float xv = 0.f;
    if (col < 1024) xv = X[((size_t)ks * TT + t) * NG3 + col];  // r,z: add x-gate now
    Gw[ks * NG3 + col] = gout + xv;

    grid_bar(flags, wg, (unsigned)(t + 1));

    // ---- phase 2: redundant LN + gates + h update (every WG, all 16 b) ----
    const float* Grow = Gb + (size_t)(t & 1) * (BB * NG3) + (size_t)b2 * NG3;
    const float* Xrow = X + ((size_t)b2 * TT + t) * NG3;

    float gr[32], gz[32], np_[32];
    float s = 0.f, s2 = 0.f;
#pragma unroll
    for (int i = 0; i < 8; ++i) {
      int j2 = l16 * 4 + i * 64;
      *reinterpret_cast<float4*>(&gr[i * 4]) = *reinterpret_cast<const float4*>(&Grow[j2]);
#pragma unroll
      for (int q = 0; q < 4; ++q) { float v = gr[i * 4 + q]; s += v; s2 += v * v; }
    }
    s = red16_(s); s2 = red16_(s2);
    const float mr = s * (1.f / 512.f);
    const float rsr = rsqrtf(s2 * (1.f / 512.f) - mr * mr + LNEPS);

    s = 0.f; s2 = 0.f;
#pragma unroll
    for (int i = 0; i < 8; ++i) {
      int j2 = l16 * 4 + i * 64;
      float gn[4], xn[4];
      *reinterpret_cast<float4*>(gn) = *reinterpret_cast<const float4*>(&Grow[1024 + j2]);
      *reinterpret_cast<float4*>(xn) = *reinterpret_cast<const float4*>(&Xrow[1024 + j2]);
#pragma unroll
      for (int q = 0; q < 4; ++q) {
        float rv = sigmoidf_((gr[i * 4 + q] - mr) * rsr * lnw[j2 + q] + lnb[j2 + q]);
        float v = xn[q] + rv * gn[q];
        np_[i * 4 + q] = v; s += v; s2 += v * v;
      }
    }
    s = red16_(s); s2 = red16_(s2);
    const float mn = s * (1.f / 512.f);
    const float rsn = rsqrtf(s2 * (1.f / 512.f) - mn * mn + LNEPS);

    s = 0.f; s2 = 0.f;
#pragma unroll
    for (int i = 0; i < 8; ++i) {
      int j2 = l16 * 4 + i * 64;
      *reinterpret_cast<float4*>(&gz[i * 4]) = *reinterpret_cast<const float4*>(&Grow[512 + j2]);
#pragma unroll
      for (int q = 0; q < 4; ++q) { float v = gz[i * 4 + q]; s += v; s2 += v * v; }
    }
    s = red16_(s); s2 = red16_(s2);
    const float mz = s * (1.f / 512.f);
    const float rsz = rsqrtf(s2 * (1.f / 512.f) - mz * mz + LNEPS);

#pragma unroll
    for (int i = 0; i < 8; ++i) {
      int j2 = l16 * 4 + i * 64;
      int off = physc(l16 + i * 16) << 2;  // swizzled float offset in h_s row
      float hold[4], hv[4], rs4[4];
      *reinterpret_cast<float4*>(hold) = *reinterpret_cast<const float4*>(&h_s[b2][off]);
      if (resid)
        *reinterpret_cast<float4*>(rs4) =
            *reinterpret_cast<const float4*>(&resid[((size_t)b2 * TT + t) * HH + j2]);
#pragma unroll
      for (int q = 0; q < 4; ++q) {
        float z = sigmoidf_((gz[i * 4 + q] - mz) * rsz * lnw[512 + j2 + q] + lnb[512 + j2 + q]);
        float n = tanhf_((np_[i * 4 + q] - mn) * rsn * lnw[1024 + j2 + q] + lnb[1024 + j2 + q]);
        float hnv = (1.f - z) * n + z * hold[q];
        if (resid) hnv += rs4[q];
        hv[q] = hnv;
      }
      *reinterpret_cast<float4*>(&h_s[b2][off]) = *reinterpret_cast<const float4*>(hv);
      if (wg == b2) {
        *reinterpret_cast<float4*>(&hout[((size_t)b2 * TT + t) * HH + j2]) =
            *reinterpret_cast<const float4*>(hv);
      }
    }
    __syncthreads();  // h_s updated before next phase-1 reads
  }
}

// ---------------- launch ----------------
extern "C" void kernel_launch(void* const* d_in, const int* in_sizes, int n_in,
                              void* d_out, int out_size, void* d_ws, size_t ws_size,
                              hipStream_t stream) {
  (void)in_sizes; (void)n_in; (void)out_size; (void)ws_size;
  const float* x   = (const float*)d_in[0];
  const float* Wi  = (const float*)d_in[1];  // [2][1536][512]
  const float* Wh  = (const float*)d_in[2];  // [2][1536][512]
  const float* lnw = (const float*)d_in[3];  // [2][3][512]
  const float* lnb = (const float*)d_in[4];
  float* out = (float*)d_out;

  float* X  = (float*)d_ws;                        // [24000][1536]
  float* h0 = X + (size_t)GM * NG3;                // [24000][512]
  float* Gb = h0 + (size_t)GM * HH;                // [2][16][1536]
  unsigned* flags = (unsigned*)(Gb + 2 * BB * NG3);// [2][96][64] padded flag lines

  hipMemsetAsync(flags, 0, 2 * RWG * FLAGSTRIDE * sizeof(unsigned), stream);

  dim3 ggrid(GM / 64, GN / 64);
  // layer 0 input gates
  gemm_nt<<<ggrid, 256, 0, stream>>>(x, Wi, X);
  // layer 0 scan
  gru_layer<<<RWG, 256, 0, stream>>>(Wh, X, lnw, lnb, nullptr, h0, Gb, flags);
  // layer 1 input gates (reuse X buffer)
  gemm_nt<<<ggrid, 256, 0, stream>>>(h0, Wi + (size_t)NG3 * DD, X);
  // layer 1 scan (+residual), writes final output
  gru_layer<<<RWG, 256, 0, stream>>>(Wh + (size_t)NG3 * HH, X, lnw + 3 * 512, lnb + 3 * 512,
                                     h0, out, Gb, flags + RWG * FLAGSTRIDE);
}

// Round 3
// 39772.336 us; speedup vs baseline: 2.3835x; 2.2717x over previous
//
#include <hip/hip_runtime.h>

#define BB 16
#define TT 1500
#define DD 512
#define HH 512
#define NG3 1536
#define GM (BB * TT)   /* 24000 */
#define GK 512
#define GN NG3
#define LNEPS 1e-5f
#define RWG 96
#define CPW 16
#define FLAGSTRIDE 64  /* uints -> 256B per flag line */

// ---------------- helpers ----------------
__device__ __forceinline__ float sigmoidf_(float x) { return 1.f / (1.f + __expf(-x)); }
__device__ __forceinline__ float tanhf_(float x) {
  x = fminf(15.f, fmaxf(-15.f, x));
  float e = __expf(2.f * x);
  return (e - 1.f) / (e + 1.f);
}
// sum across each 16-lane group (lane & 15)
__device__ __forceinline__ float red16_(float v) {
  v += __shfl_xor(v, 1, 64);
  v += __shfl_xor(v, 2, 64);
  v += __shfl_xor(v, 4, 64);
  v += __shfl_xor(v, 8, 64);
  return v;
}
// XOR-swizzled physical float4-chunk index for a [512]-float LDS row
__device__ __forceinline__ int physc(int lc) { return (lc & ~7) | ((lc ^ (lc >> 3)) & 7); }

// fine-grained agent-coherent ops (sc1 path, NO cache maintenance)
__device__ __forceinline__ void st_agent_f(float* p, float v) {
  __hip_atomic_store(p, v, __ATOMIC_RELAXED, __HIP_MEMORY_SCOPE_AGENT);
}
__device__ __forceinline__ float2 ld2_agent(const float* p) {
  union { unsigned long long u; float2 f; } c;
  c.u = __hip_atomic_load((const unsigned long long*)p, __ATOMIC_RELAXED,
                          __HIP_MEMORY_SCOPE_AGENT);
  return c.f;
}

// ---------------- big GEMM: C[M,N] = A[M,K] @ W[N,K]^T (fp32) ----------------
__global__ __launch_bounds__(256) void gemm_nt(const float* __restrict__ A,
                                               const float* __restrict__ W,
                                               float* __restrict__ C) {
  __shared__ __align__(16) float As[32][68];
  __shared__ __align__(16) float Ws[32][68];
  const int m0 = blockIdx.x * 64;
  const int n0 = blockIdx.y * 64;
  const int tid = threadIdx.x;
  const int tm = tid & 15, tn = tid >> 4;
  float acc[4][4] = {};
  for (int k0 = 0; k0 < GK; k0 += 32) {
#pragma unroll
    for (int u = 0; u < 2; ++u) {
      int idx = tid + u * 256;
      int r = idx >> 3;
      int kq = (idx & 7) * 4;
      float4 a = *reinterpret_cast<const float4*>(&A[(size_t)(m0 + r) * GK + k0 + kq]);
      As[kq + 0][r] = a.x; As[kq + 1][r] = a.y; As[kq + 2][r] = a.z; As[kq + 3][r] = a.w;
      float4 w = *reinterpret_cast<const float4*>(&W[(size_t)(n0 + r) * GK + k0 + kq]);
      Ws[kq + 0][r] = w.x; Ws[kq + 1][r] = w.y; Ws[kq + 2][r] = w.z; Ws[kq + 3][r] = w.w;
    }
    __syncthreads();
#pragma unroll
    for (int kk = 0; kk < 32; ++kk) {
      float a[4], w[4];
      *reinterpret_cast<float4*>(a) = *reinterpret_cast<const float4*>(&As[kk][tm * 4]);
      *reinterpret_cast<float4*>(w) = *reinterpret_cast<const float4*>(&Ws[kk][tn * 4]);
#pragma unroll
      for (int i = 0; i < 4; ++i)
#pragma unroll
        for (int q = 0; q < 4; ++q)
          acc[i][q] = fmaf(a[i], w[q], acc[i][q]);
    }
    __syncthreads();
  }
#pragma unroll
  for (int i = 0; i < 4; ++i) {
    float4 v = make_float4(acc[i][0], acc[i][1], acc[i][2], acc[i][3]);
    *reinterpret_cast<float4*>(&C[(size_t)(m0 + tm * 4 + i) * GN + n0 + tn * 4]) = v;
  }
}

// ---------------- fence-free flag barrier ----------------
// Producer data (G) goes out via sc1 atomic stores; per-wave vmcnt(0) drain,
// then flag store (relaxed, agent). Consumers poll flags with relaxed agent
// loads and read G with sc1 atomic loads -> no buffer_wbl2 / buffer_inv ever.
__device__ __forceinline__ void grid_bar(unsigned* flags, int wg, unsigned tval) {
  asm volatile("s_waitcnt vmcnt(0)" ::: "memory");  // this wave's G stores are at L3
  __syncthreads();                                  // all waves drained
  if (threadIdx.x == 0)
    __hip_atomic_store(&flags[(size_t)wg * FLAGSTRIDE], tval, __ATOMIC_RELAXED,
                       __HIP_MEMORY_SCOPE_AGENT);
  if (threadIdx.x < RWG) {
    while (__hip_atomic_load(&flags[(size_t)threadIdx.x * FLAGSTRIDE], __ATOMIC_RELAXED,
                             __HIP_MEMORY_SCOPE_AGENT) < tval)
      __builtin_amdgcn_s_sleep(1);
  }
  __syncthreads();
  asm volatile("" ::: "memory");  // compiler barrier only
}

// ---------------- persistent GRU layer scan ----------------
__global__ __launch_bounds__(256, 1) void gru_layer(
    const float* __restrict__ Wh,    // [1536][512] this layer
    const float* __restrict__ X,     // [BB][TT][1536] precomputed input gates
    const float* __restrict__ lnw,   // [3][512] this layer
    const float* __restrict__ lnb,   // [3][512]
    const float* __restrict__ resid, // null (layer0) or h0 [BB][TT][HH]
    float* __restrict__ hout,        // h0 (layer0) or out (layer1): [BB][TT][HH]
    float* __restrict__ Gb,          // [2][BB][1536] double-buffered pre-acts
    unsigned* __restrict__ flags) {
  __shared__ __align__(16) float h_s[BB][512];  // private copy of h (chunk-swizzled rows)

  const int tid = threadIdx.x;
  const int wg = blockIdx.x;
  const int j0 = wg * CPW;

  const int lane = tid & 63;
  const int wv = tid >> 6;
  const int ks = lane & 15;       // K-chunk index: k in [ks*32, ks*32+32)
  const int cq = lane >> 4;       // column within wave (0..3)
  const int col = j0 + wv * 4 + cq;

  // persistent weights in registers: Wh[col][ks*32 .. +32)
  float wreg[32];
#pragma unroll
  for (int q = 0; q < 8; ++q)
    *reinterpret_cast<float4*>(&wreg[q * 4]) =
        *reinterpret_cast<const float4*>(&Wh[(size_t)col * 512 + ks * 32 + q * 4]);

  // h0 = 0
  for (int idx = tid; idx < BB * 512; idx += 256) (&h_s[0][0])[idx] = 0.f;
  __syncthreads();

  const int b2 = (tid >> 6) * 4 + (lane >> 4);  // phase-2: batch row (16 lanes each)
  const int l16 = lane & 15;

  for (int t = 0; t < TT; ++t) {
    // ---- phase 1: h_gates, thread = (col, K-chunk), reduce over 16 chunks ----
    float gout = 0.f;
#pragma unroll 4
    for (int b = 0; b < 16; ++b) {
      const float* hrow = &h_s[b][0];
      float p = 0.f;
#pragma unroll
      for (int i = 0; i < 8; ++i) {
        float hv[4];
        *reinterpret_cast<float4*>(hv) =
            *reinterpret_cast<const float4*>(&hrow[(((ks << 3) | ((i ^ ks) & 7)) << 2)]);
        p = fmaf(hv[0], wreg[i * 4 + 0], p);
        p = fmaf(hv[1], wreg[i * 4 + 1], p);
        p = fmaf(hv[2], wreg[i * 4 + 2], p);
        p = fmaf(hv[3], wreg[i * 4 + 3], p);
      }
      p = red16_(p);
      if (ks == b) gout = p;  // each lane keeps the row matching its ks
    }
    {
      float xv = 0.f;
      if (col < 1024) xv = X[((size_t)ks * TT + t) * NG3 + col];  // r,z: add x-gate now
      float* Gw = Gb + (size_t)(t & 1) * (BB * NG3);
      st_agent_f(&Gw[ks * NG3 + col], gout + xv);
    }

    // prefetch X n-gate row (plain cached loads; immutable) before the wait
    const float* Xrow = X + ((size_t)b2 * TT + t) * NG3;
    float xn[32];
#pragma unroll
    for (int i = 0; i < 8; ++i)
      *reinterpret_cast<float4*>(&xn[i * 4]) =
          *reinterpret_cast<const float4*>(&Xrow[1024 + l16 * 4 + i * 64]);

    grid_bar(flags, wg, (unsigned)(t + 1));

    // ---- phase 2: redundant LN + gates + h update (every WG, all 16 b) ----
    const float* Grow = Gb + (size_t)(t & 1) * (BB * NG3) + (size_t)b2 * NG3;

    float gr[32], gz[32], np_[32];
    float s = 0.f, s2 = 0.f;
#pragma unroll
    for (int i = 0; i < 8; ++i) {
      int j2 = l16 * 4 + i * 64;
      float2 a = ld2_agent(&Grow[j2]);
      float2 b = ld2_agent(&Grow[j2 + 2]);
      gr[i * 4 + 0] = a.x; gr[i * 4 + 1] = a.y; gr[i * 4 + 2] = b.x; gr[i * 4 + 3] = b.y;
#pragma unroll
      for (int q = 0; q < 4; ++q) { float v = gr[i * 4 + q]; s += v; s2 += v * v; }
    }
    s = red16_(s); s2 = red16_(s2);
    const float mr = s * (1.f / 512.f);
    const float rsr = rsqrtf(s2 * (1.f / 512.f) - mr * mr + LNEPS);

    s = 0.f; s2 = 0.f;
#pragma unroll
    for (int i = 0; i < 8; ++i) {
      int j2 = l16 * 4 + i * 64;
      float2 a = ld2_agent(&Grow[1024 + j2]);
      float2 b = ld2_agent(&Grow[1024 + j2 + 2]);
      float gn[4] = {a.x, a.y, b.x, b.y};
#pragma unroll
      for (int q = 0; q < 4; ++q) {
        float rv = sigmoidf_((gr[i * 4 + q] - mr) * rsr * lnw[j2 + q] + lnb[j2 + q]);
        float v = xn[i * 4 + q] + rv * gn[q];
        np_[i * 4 + q] = v; s += v; s2 += v * v;
      }
    }
    s = red16_(s); s2 = red16_(s2);
    const float mn = s * (1.f / 512.f);
    const float rsn = rsqrtf(s2 * (1.f / 512.f) - mn * mn + LNEPS);

    s = 0.f; s2 = 0.f;
#pragma unroll
    for (int i = 0; i < 8; ++i) {
      int j2 = l16 * 4 + i * 64;
      float2 a = ld2_agent(&Grow[512 + j2]);
      float2 b = ld2_agent(&Grow[512 + j2 + 2]);
      gz[i * 4 + 0] = a.x; gz[i * 4 + 1] = a.y; gz[i * 4 + 2] = b.x; gz[i * 4 + 3] = b.y;
#pragma unroll
      for (int q = 0; q < 4; ++q) { float v = gz[i * 4 + q]; s += v; s2 += v * v; }
    }
    s = red16_(s); s2 = red16_(s2);
    const float mz = s * (1.f / 512.f);
    const float rsz = rsqrtf(s2 * (1.f / 512.f) - mz * mz + LNEPS);

#pragma unroll
    for (int i = 0; i < 8; ++i) {
      int j2 = l16 * 4 + i * 64;
      int off = physc(l16 + i * 16) << 2;  // swizzled float offset in h_s row
      float hold[4], hv[4], rs4[4];
      *reinterpret_cast<float4*>(hold) = *reinterpret_cast<const float4*>(&h_s[b2][off]);
      if (resid)
        *reinterpret_cast<float4*>(rs4) =
            *reinterpret_cast<const float4*>(&resid[((size_t)b2 * TT + t) * HH + j2]);
#pragma unroll
      for (int q = 0; q < 4; ++q) {
        float z = sigmoidf_((gz[i * 4 + q] - mz) * rsz * lnw[512 + j2 + q] + lnb[512 + j2 + q]);
        float n = tanhf_((np_[i * 4 + q] - mn) * rsn * lnw[1024 + j2 + q] + lnb[1024 + j2 + q]);
        float hnv = (1.f - z) * n + z * hold[q];
        if (resid) hnv += rs4[q];
        hv[q] = hnv;
      }
      *reinterpret_cast<float4*>(&h_s[b2][off]) = *reinterpret_cast<const float4*>(hv);
      if (wg == b2) {
        *reinterpret_cast<float4*>(&hout[((size_t)b2 * TT + t) * HH + j2]) =
            *reinterpret_cast<const float4*>(hv);
      }
    }
    __syncthreads();  // h_s updated before next phase-1 reads
  }
}

// ---------------- launch ----------------
extern "C" void kernel_launch(void* const* d_in, const int* in_sizes, int n_in,
                              void* d_out, int out_size, void* d_ws, size_t ws_size,
                              hipStream_t stream) {
  (void)in_sizes; (void)n_in; (void)out_size; (void)ws_size;
  const float* x   = (const float*)d_in[0];
  const float* Wi  = (const float*)d_in[1];  // [2][1536][512]
  const float* Wh  = (const float*)d_in[2];  // [2][1536][512]
  const float* lnw = (const float*)d_in[3];  // [2][3][512]
  const float* lnb = (const float*)d_in[4];
  float* out = (float*)d_out;

  float* X  = (float*)d_ws;                        // [24000][1536]
  float* h0 = X + (size_t)GM * NG3;                // [24000][512]
  float* Gb = h0 + (size_t)GM * HH;                // [2][16][1536]
  unsigned* flags = (unsigned*)(Gb + 2 * BB * NG3);// [2][96][64] padded flag lines

  hipMemsetAsync(flags, 0, 2 * RWG * FLAGSTRIDE * sizeof(unsigned), stream);

  dim3 ggrid(GM / 64, GN / 64);
  // layer 0 input gates
  gemm_nt<<<ggrid, 256, 0, stream>>>(x, Wi, X);
  // layer 0 scan
  gru_layer<<<RWG, 256, 0, stream>>>(Wh, X, lnw, lnb, nullptr, h0, Gb, flags);
  // layer 1 input gates (reuse X buffer)
  gemm_nt<<<ggrid, 256, 0, stream>>>(h0, Wi + (size_t)NG3 * DD, X);
  // layer 1 scan (+residual), writes final output
  gru_layer<<<RWG, 256, 0, stream>>>(Wh + (size_t)NG3 * HH, X, lnw + 3 * 512, lnb + 3 * 512,
                                     h0, out, Gb, flags + RWG * FLAGSTRIDE);
}